// Round 3
// baseline (1484.021 us; speedup 1.0000x reference)
//
#include <hip/hip_runtime.h>

typedef __bf16 bf16x8 __attribute__((ext_vector_type(8)));
typedef float f32x4 __attribute__((ext_vector_type(4)));

#define MFMA16(a, b, c) __builtin_amdgcn_mfma_f32_16x16x32_bf16(a, b, c, 0, 0, 0)

// async global->LDS, 16B per lane; LDS dest is wave-uniform base + lane*16
__device__ __forceinline__ void gload_lds16(const void* g, void* l) {
  __builtin_amdgcn_global_load_lds(
      (const __attribute__((address_space(1))) void*)(unsigned long long)g,
      (__attribute__((address_space(3))) void*)(unsigned int)(unsigned long long)l,
      16, 0, 0);
}

// ---------------- K0: convert 3x512x512 fp32 weights -> bf16 ----------------
__global__ void cvt_w_kernel(const float* __restrict__ wq, const float* __restrict__ wk,
                             const float* __restrict__ wv, __bf16* __restrict__ w) {
  int i = blockIdx.x * 256 + threadIdx.x;  // grid 1024 -> 262144
  w[i]          = (__bf16)wq[i];
  w[i + 262144] = (__bf16)wk[i];
  w[i + 524288] = (__bf16)wv[i];
}

// ---------------- K1: LayerNorm rows of 512, fp32 -> bf16 -------------------
// input rows in (b,t,n) order; output rows PERMUTED to (b,n,t) order so the
// QKV GEMM can emit (b,n,h,t,d)-contiguous tensors for attention.
__global__ __launch_bounds__(256) void ln_kernel(
    const float* __restrict__ x, const float* __restrict__ cx,
    const float* __restrict__ g, const float* __restrict__ bet,
    __bf16* __restrict__ xn) {
  int wave = threadIdx.x >> 6, lane = threadIdx.x & 63;
  long row = (long)blockIdx.x * 4 + wave;
  int rloc = (row < 98304) ? (int)row : (int)(row - 98304);
  const float* src = (row < 98304) ? (x + row * 512) : (cx + (long)rloc * 512);
  const f32x4* p = (const f32x4*)(src + lane * 8);
  f32x4 a = p[0], b = p[1];
  float s  = a[0] + a[1] + a[2] + a[3] + b[0] + b[1] + b[2] + b[3];
  float s2 = a[0]*a[0] + a[1]*a[1] + a[2]*a[2] + a[3]*a[3]
           + b[0]*b[0] + b[1]*b[1] + b[2]*b[2] + b[3]*b[3];
  for (int d = 1; d < 64; d <<= 1) { s += __shfl_xor(s, d, 64); s2 += __shfl_xor(s2, d, 64); }
  float mean = s * (1.0f / 512.0f);
  float var  = s2 * (1.0f / 512.0f) - mean * mean;
  float rs = rsqrtf(var + 1e-5f);
  const f32x4* gp = (const f32x4*)(g + lane * 8);
  const f32x4* bp = (const f32x4*)(bet + lane * 8);
  f32x4 g0 = gp[0], g1 = gp[1], b0 = bp[0], b1 = bp[1];
  bf16x8 o;
  for (int j = 0; j < 4; ++j) o[j]     = (__bf16)((a[j] - mean) * rs * g0[j] + b0[j]);
  for (int j = 0; j < 4; ++j) o[4 + j] = (__bf16)((b[j] - mean) * rs * g1[j] + b1[j]);
  // permute (b,t,n) -> (b,n,t)
  int b_ = rloc / 6144;
  int rem = rloc - b_ * 6144;
  int t_ = rem / 24;
  int n_ = rem - t_ * 24;
  long drow = (long)(b_ * 24 + n_) * 256 + t_ + ((row < 98304) ? 0 : 98304);
  *(bf16x8*)(xn + drow * 512 + lane * 8) = o;
}

// ---------------- K2: QKV projection GEMM (NT), 128x128 tile, BK=64 ---------
// z=0: Q = xn @ Wq^T ; z=1: K = cn @ Wk^T ; z=2: V = cn @ Wv^T
// A rows are in (b,n,t) order; epilogue splits col=(h,d) and writes
// C in (b,n,h,t,d) layout: addr = ((m>>8)*8+h)*16384 + (m&255)*64 + d.
__global__ __launch_bounds__(256) void gemm_qkv_kernel(
    const __bf16* __restrict__ act, const __bf16* __restrict__ w,
    __bf16* __restrict__ outqkv) {
  int z = blockIdx.z;
  const __bf16* A = act + (z ? (long)50331648 : 0);   // cn for K,V
  const __bf16* B = w + (long)z * 262144;
  __bf16* C = outqkv + (long)z * 50331648;
  int m0 = blockIdx.x * 128, n0 = blockIdx.y * 128;
  int tid = threadIdx.x, wave = tid >> 6, lane = tid & 63;
  int q4 = lane >> 4, cl = lane & 15;
  int wm = wave & 1, wn = wave >> 1;
  __shared__ __bf16 As[128 * 64];
  __shared__ __bf16 Bs[128 * 64];
  f32x4 acc[4][4] = {};
  for (int kb = 0; kb < 512; kb += 64) {
    for (int i = 0; i < 4; ++i) {
      int t = i * 256 + tid;
      int row = t >> 3;
      int col = (t & 7) * 8;
      gload_lds16(A + (long)(m0 + row) * 512 + kb + col, (char*)As + (i * 256 + wave * 64) * 16);
      gload_lds16(B + (long)(n0 + row) * 512 + kb + col, (char*)Bs + (i * 256 + wave * 64) * 16);
    }
    __syncthreads();
    for (int kc = 0; kc < 2; ++kc) {
      bf16x8 af[4], bfr[4];
      for (int mt = 0; mt < 4; ++mt)
        af[mt] = *(const bf16x8*)(As + (wm * 64 + mt * 16 + cl) * 64 + kc * 32 + q4 * 8);
      for (int nt = 0; nt < 4; ++nt)
        bfr[nt] = *(const bf16x8*)(Bs + (wn * 64 + nt * 16 + cl) * 64 + kc * 32 + q4 * 8);
      for (int mt = 0; mt < 4; ++mt)
        for (int nt = 0; nt < 4; ++nt)
          acc[mt][nt] = MFMA16(af[mt], bfr[nt], acc[mt][nt]);
    }
    __syncthreads();
  }
  for (int mt = 0; mt < 4; ++mt)
    for (int nt = 0; nt < 4; ++nt) {
      int col = n0 + wn * 64 + nt * 16 + cl;
      int hh = col >> 6, dd = col & 63;
      int mbase = m0 + wm * 64 + mt * 16 + q4 * 4;
      for (int r = 0; r < 4; ++r) {
        int m = mbase + r;
        long addr = ((long)((m >> 8) * 8 + hh) << 14) + ((m & 255) << 6) + dd;
        C[addr] = (__bf16)acc[mt][nt][r];
      }
    }
}

// ---------------- K3: attention + softmax + residual + output ---------------
// one block per (b,n,h); Q/K/V contiguous 256x64 bf16 slabs per block.
// Swapped QK^T (A=K, B=Q), exact online softmax over 4 chunks of 64 keys,
// P kept in-register (keys permuted to match Vt column order).
// LDS = Vt only (33792 B); launch_bounds(256,4) -> target 4 blocks/CU.
__global__ __launch_bounds__(256, 4) void attn_kernel(
    const __bf16* __restrict__ Q, const __bf16* __restrict__ K,
    const __bf16* __restrict__ V, const float* __restrict__ x,
    float* __restrict__ out) {
  int blk = blockIdx.x;            // (b*24+n)*8 + h, 3072 total
  int h = blk & 7;
  int bn = blk >> 3;
  int n_ = bn % 24;
  int b_ = bn / 24;
  const __bf16* Qh = Q + (long)blk * 16384;
  const __bf16* Kh = K + (long)blk * 16384;
  const __bf16* Vh = V + (long)blk * 16384;
  long xbase = (long)b_ * 3145728 + (long)n_ * 512 + h * 64;  // + t*12288 + d

  int tid = threadIdx.x, wave = tid >> 6, lane = tid & 63;
  int q4 = lane >> 4, cl = lane & 15;

  __shared__ __align__(16) __bf16 Vt[64][264];  // [d][perm(key)], +8 pad

  // ---- stage V transposed + key-permuted; thread handles key = tid
  {
    int key = tid;
    // within each 32-key chunk: key = q4*4 + half*16 + j  ->  col = q4*8 + half*4 + j
    int colp = (key & ~31) | ((key & 12) << 1) | ((key & 16) >> 2) | (key & 3);
    const __bf16* vrow = Vh + key * 64;
    for (int i = 0; i < 8; ++i) {
      bf16x8 v = *(const bf16x8*)(vrow + i * 8);
      for (int j = 0; j < 8; ++j) Vt[i * 8 + j][colp] = v[j];
    }
  }
  __syncthreads();

  const float c_exp = 0.125f * 1.44269504088896f;  // fold 1/sqrt(64) into exp2
  for (int iter = 0; iter < 4; ++iter) {
    int qt = wave * 4 + iter;  // 16 queries per iter per wave
    const __bf16* qrow = Qh + (qt * 16 + cl) * 64 + q4 * 8;
    bf16x8 qb0 = *(const bf16x8*)(qrow);
    bf16x8 qb1 = *(const bf16x8*)(qrow + 32);
    f32x4 o[4] = {};
    float m = -1e30f, l = 0.0f;
#pragma unroll
    for (int c = 0; c < 4; ++c) {
      // ---- QK^T for 64 keys: K read straight from global (contiguous slab)
      f32x4 s4[4];
#pragma unroll
      for (int kk = 0; kk < 4; ++kk) {
        const __bf16* krow = Kh + ((c * 4 + kk) * 16 + cl) * 64 + q4 * 8;
        bf16x8 ka0 = *(const bf16x8*)(krow);
        bf16x8 ka1 = *(const bf16x8*)(krow + 32);
        f32x4 a = {};
        a = MFMA16(ka0, qb0, a);   // A=K, B=Q -> D[key][q]
        a = MFMA16(ka1, qb1, a);
        s4[kk] = a;
      }
      // ---- online softmax update (exact; skip rescale when max unchanged)
      float cm = -1e30f;
#pragma unroll
      for (int kk = 0; kk < 4; ++kk)
#pragma unroll
        for (int r = 0; r < 4; ++r) cm = fmaxf(cm, s4[kk][r]);
      cm = fmaxf(cm, __shfl_xor(cm, 16, 64));
      cm = fmaxf(cm, __shfl_xor(cm, 32, 64));
      if (!__all(cm <= m)) {
        float mn = fmaxf(m, cm);
        float sc = exp2f((m - mn) * c_exp);
        m = mn;
        l *= sc;
        // o rows are queries q4*4+r; sc is indexed by q=cl (uniform over q4)
        float s0 = __shfl(sc, q4 * 4 + 0, 64);
        float s1 = __shfl(sc, q4 * 4 + 1, 64);
        float s2 = __shfl(sc, q4 * 4 + 2, 64);
        float s3 = __shfl(sc, q4 * 4 + 3, 64);
#pragma unroll
        for (int db = 0; db < 4; ++db) {
          o[db][0] *= s0; o[db][1] *= s1; o[db][2] *= s2; o[db][3] *= s3;
        }
      }
      // ---- exp, accumulate l, pack P into A-frags (permuted key order)
      bf16x8 pa0, pa1;
#pragma unroll
      for (int r = 0; r < 4; ++r) {
        float p0 = exp2f((s4[0][r] - m) * c_exp);
        float p1 = exp2f((s4[1][r] - m) * c_exp);
        float p2 = exp2f((s4[2][r] - m) * c_exp);
        float p3 = exp2f((s4[3][r] - m) * c_exp);
        l += (p0 + p1) + (p2 + p3);
        pa0[r] = (__bf16)p0; pa0[4 + r] = (__bf16)p1;
        pa1[r] = (__bf16)p2; pa1[4 + r] = (__bf16)p3;
      }
      // ---- PV for this 64-key chunk from padded Vt (conflict-free b128)
#pragma unroll
      for (int db = 0; db < 4; ++db) {
        bf16x8 vb0 = *(const bf16x8*)(&Vt[db * 16 + cl][c * 64 + q4 * 8]);
        bf16x8 vb1 = *(const bf16x8*)(&Vt[db * 16 + cl][c * 64 + 32 + q4 * 8]);
        o[db] = MFMA16(pa0, vb0, o[db]);
        o[db] = MFMA16(pa1, vb1, o[db]);
      }
    }
    // ---- finish softmax denominator, normalize, residual, store
    l += __shfl_xor(l, 16, 64);
    l += __shfl_xor(l, 32, 64);
#pragma unroll
    for (int r = 0; r < 4; ++r) {
      float lr = __shfl(l, q4 * 4 + r, 64);
      float inv = 1.0f / lr;
      long trow = xbase + (long)(qt * 16 + q4 * 4 + r) * 12288;
#pragma unroll
      for (int db = 0; db < 4; ++db) {
        long addr = trow + db * 16 + cl;
        out[addr] = x[addr] + o[db][r] * inv;
      }
    }
  }
}

extern "C" void kernel_launch(void* const* d_in, const int* in_sizes, int n_in,
                              void* d_out, int out_size, void* d_ws, size_t ws_size,
                              hipStream_t stream) {
  const float* x     = (const float*)d_in[0];
  const float* cx    = (const float*)d_in[1];
  const float* gamma = (const float*)d_in[2];
  const float* beta  = (const float*)d_in[3];
  const float* Wq    = (const float*)d_in[4];
  const float* Wk    = (const float*)d_in[5];
  const float* Wv    = (const float*)d_in[6];
  float* out = (float*)d_out;
  char* ws = (char*)d_ws;

  // workspace layout (bytes):
  //   [0,            1572864)   Wqkv bf16  (3*512*512*2)
  //   [1572864,      202899456) xn|cn bf16 (2*98304*512*2), rows in (b,n,t)
  //   [202899456,    504889344) Q|K|V bf16 (3*98304*512*2), (b,n,h,t,d)
  __bf16* Wb = (__bf16*)(ws);
  __bf16* xn = (__bf16*)(ws + 1572864);
  __bf16* Qb = (__bf16*)(ws + 202899456);

  cvt_w_kernel<<<1024, 256, 0, stream>>>(Wq, Wk, Wv, Wb);
  ln_kernel<<<49152, 256, 0, stream>>>(x, cx, gamma, beta, xn);
  gemm_qkv_kernel<<<dim3(768, 4, 3), 256, 0, stream>>>(xn, Wb, Qb);
  attn_kernel<<<3072, 256, 0, stream>>>(Qb, Qb + 50331648, Qb + 100663296, x, out);
}